// Round 1
// baseline (52.873 us; speedup 1.0000x reference)
//
#include <hip/hip_runtime.h>
#include <math.h>

#define NCLS 3
#define NYAW 2
#define NYG 160
#define NXG 160
#define NB 32
#define NANCH (NYAW * NYG * NXG)   /* 51200 */
#define DOF 7
#define EPSI 1e-8f

/* output layout (floats) */
#define OFF_GCLS 0
#define OFF_GREG (NCLS * NANCH)                    /* 153600 */
#define OFF_MCLS (OFF_GREG + NCLS * NANCH * DOF)   /* 1228800 */
#define OFF_MREG (OFF_MCLS + NANCH)                /* 1280000 */

struct BBev { float x, y, w, l, yaw; };

__device__ __forceinline__ float crossv(float ax, float ay, float bx, float by) {
    return ax * by - ay * bx;
}

/* Rotated-box IoU, mirroring the reference _pair_iou step by step.
   b1 = ground-truth box (corners first in the point list), b2 = anchor. */
__device__ float pair_iou(const BBev b1, const BBev b2) {
    /* quick reject: if bounding circles don't overlap, every mask in the
       reference is false -> inter = 0 -> iou = exactly 0.0 */
    float ddx = b1.x - b2.x, ddy = b1.y - b2.y;
    float r1 = 0.5f * sqrtf(b1.w * b1.w + b1.l * b1.l);
    float r2 = 0.5f * sqrtf(b2.w * b2.w + b2.l * b2.l);
    float rr = r1 + r2 + 1e-3f;  /* margin covers the 1e-5 inside tolerance */
    if (ddx * ddx + ddy * ddy > rr * rr) return 0.0f;

    float cs1 = cosf(b1.yaw), sn1 = sinf(b1.yaw);
    float cs2 = cosf(b2.yaw), sn2 = sinf(b2.yaw);

    float c1x[4], c1y[4], c2x[4], c2y[4];
    {
        float ux = cs1 * (b1.w * 0.5f), uy = sn1 * (b1.w * 0.5f);
        float vx = -sn1 * (b1.l * 0.5f), vy = cs1 * (b1.l * 0.5f);
        c1x[0] = b1.x + ux + vx; c1y[0] = b1.y + uy + vy;
        c1x[1] = b1.x + ux - vx; c1y[1] = b1.y + uy - vy;
        c1x[2] = b1.x - ux - vx; c1y[2] = b1.y - uy - vy;
        c1x[3] = b1.x - ux + vx; c1y[3] = b1.y - uy + vy;
    }
    {
        float ux = cs2 * (b2.w * 0.5f), uy = sn2 * (b2.w * 0.5f);
        float vx = -sn2 * (b2.l * 0.5f), vy = cs2 * (b2.l * 0.5f);
        c2x[0] = b2.x + ux + vx; c2y[0] = b2.y + uy + vy;
        c2x[1] = b2.x + ux - vx; c2y[1] = b2.y + uy - vy;
        c2x[2] = b2.x - ux - vx; c2y[2] = b2.y - uy - vy;
        c2x[3] = b2.x - ux + vx; c2y[3] = b2.y - uy + vy;
    }

    /* collect valid points in reference concat order: c1, c2, ipts(i-major) */
    float qx[24], qy[24];
    int n = 0;

    for (int i = 0; i < 4; i++) {  /* c1 corners inside b2 */
        float rx = c1x[i] - b2.x, ry = c1y[i] - b2.y;
        float du = rx * cs2 + ry * sn2;
        float dv = -rx * sn2 + ry * cs2;
        if (fabsf(du) <= b2.w * 0.5f + 1e-5f && fabsf(dv) <= b2.l * 0.5f + 1e-5f) {
            qx[n] = c1x[i]; qy[n] = c1y[i]; n++;
        }
    }
    for (int i = 0; i < 4; i++) {  /* c2 corners inside b1 */
        float rx = c2x[i] - b1.x, ry = c2y[i] - b1.y;
        float du = rx * cs1 + ry * sn1;
        float dv = -rx * sn1 + ry * cs1;
        if (fabsf(du) <= b1.w * 0.5f + 1e-5f && fabsf(dv) <= b1.l * 0.5f + 1e-5f) {
            qx[n] = c2x[i]; qy[n] = c2y[i]; n++;
        }
    }
    for (int i = 0; i < 4; i++) {  /* edge-edge intersections */
        float d1x = c1x[(i + 1) & 3] - c1x[i];
        float d1y = c1y[(i + 1) & 3] - c1y[i];
        for (int j = 0; j < 4; j++) {
            float d2x = c2x[(j + 1) & 3] - c2x[j];
            float d2y = c2y[(j + 1) & 3] - c2y[j];
            float den = crossv(d1x, d1y, d2x, d2y);
            if (fabsf(den) < EPSI) continue;
            float qpx = c2x[j] - c1x[i], qpy = c2y[j] - c1y[i];
            float t = crossv(qpx, qpy, d2x, d2y) / den;
            float s = crossv(qpx, qpy, d1x, d1y) / den;
            if (t >= 0.0f && t <= 1.0f && s >= 0.0f && s <= 1.0f) {
                qx[n] = c1x[i] + t * d1x;
                qy[n] = c1y[i] + t * d1y;
                n++;
            }
        }
    }

    float inter = 0.0f;
    if (n > 0) {
        float sx = 0.0f, sy = 0.0f;
        for (int k = 0; k < n; k++) { sx += qx[k]; sy += qy[k]; }
        float cx = sx / (float)n, cy = sy / (float)n;

        float ang[24];
        for (int k = 0; k < n; k++) ang[k] = atan2f(qy[k] - cy, qx[k] - cx);

        /* stable insertion sort by angle (matches stable argsort) */
        for (int k = 1; k < n; k++) {
            float a = ang[k], x = qx[k], y = qy[k];
            int m = k - 1;
            while (m >= 0 && ang[m] > a) {
                ang[m + 1] = ang[m]; qx[m + 1] = qx[m]; qy[m + 1] = qy[m];
                m--;
            }
            ang[m + 1] = a; qx[m + 1] = x; qy[m + 1] = y;
        }

        float area = 0.0f;
        for (int k = 0; k < n; k++) {
            int kn = (k + 1 == n) ? 0 : k + 1;
            area += qx[k] * qy[kn] - qx[kn] * qy[k];
        }
        inter = 0.5f * fabsf(area);
    }

    float uni = b1.w * b1.l + b2.w * b2.l - inter;
    float iou = inter / fmaxf(uni, EPSI);
    return fminf(fmaxf(iou, 0.0f), 1.0f);
}

__global__ void iou_kernel(const float* __restrict__ boxes,
                           const float* __restrict__ anchors,
                           const int* __restrict__ cls,
                           float* __restrict__ iou_mat,
                           float* __restrict__ maxval,
                           int* __restrict__ argmax,
                           float* __restrict__ highest) {
    __shared__ BBev sb[NB];
    __shared__ int scls[NB];
    int tid = threadIdx.x;
    if (tid < NB) {
        const float* bp = boxes + tid * DOF;
        sb[tid].x = bp[0]; sb[tid].y = bp[1];
        sb[tid].w = bp[3]; sb[tid].l = bp[4];
        sb[tid].yaw = bp[6];
        scls[tid] = cls[tid];
    }
    __syncthreads();

    int idx = blockIdx.x * blockDim.x + tid;
    if (idx >= NCLS * NANCH) return;
    int c = idx / NANCH;
    int a = idx - c * NANCH;

    const float* ap = anchors + (size_t)idx * DOF;
    BBev ab;
    ab.x = ap[0]; ab.y = ap[1]; ab.w = ap[3]; ab.l = ap[4]; ab.yaw = ap[6];

    float best = -INFINITY;
    int bidx = 0;
    for (int b = 0; b < NB; b++) {
        float val = -1.0f;
        if (scls[b] == c) {
            val = pair_iou(sb[b], ab);
            if (val > 0.0f) {
                /* float-as-int atomicMax valid for non-negative floats */
                atomicMax((int*)&highest[c * NB + b], __float_as_int(val));
            }
        }
        iou_mat[((size_t)(c * NB + b)) * NANCH + a] = val;
        if (val > best) { best = val; bidx = b; }  /* strict > = first-index argmax */
    }
    maxval[idx] = best;
    argmax[idx] = bidx;
}

__global__ void label_kernel(const float* __restrict__ iou_mat,
                             const float* __restrict__ maxval,
                             const float* __restrict__ highest,
                             const int* __restrict__ cls,
                             int* __restrict__ labels) {
    int idx = blockIdx.x * blockDim.x + threadIdx.x;
    if (idx >= NCLS * NANCH) return;
    int c = idx / NANCH;
    int a = idx - c * NANCH;

    float low  = (c == 0) ? 0.45f : 0.35f;
    float high = (c == 0) ? 0.60f : 0.50f;
    float mv = maxval[idx];
    int lab = (mv >= high) ? 1 : ((mv >= low) ? -1 : 0);

    if (lab != 1) {  /* low-quality promotion: anchor is some valid box's row max */
        for (int b = 0; b < NB; b++) {
            if (cls[b] == c) {
                float h = highest[c * NB + b];
                if (h > 0.0f && iou_mat[((size_t)(c * NB + b)) * NANCH + a] == h) {
                    lab = 1;
                    break;
                }
            }
        }
    }
    labels[idx] = lab;
}

__global__ void out_kernel(const float* __restrict__ boxes,
                           const float* __restrict__ anchors,
                           const int* __restrict__ labels_in,
                           const int* __restrict__ argmax,
                           float* __restrict__ out) {
    int s = blockIdx.x * blockDim.x + threadIdx.x;
    if (s >= NANCH) return;

    int lab[NCLS];
    for (int c = 0; c < NCLS; c++) lab[c] = labels_in[c * NANCH + s];

    /* ambiguous: >1 positives across classes -> all -1 */
    int pos = 0;
    for (int c = 0; c < NCLS; c++) pos += (lab[c] == 1);
    if (pos > 1) { for (int c = 0; c < NCLS; c++) lab[c] = -1; }

    /* negative & ~positive -> all 0 (on post-ambiguity labels) */
    bool neg = false; pos = 0;
    for (int c = 0; c < NCLS; c++) { neg |= (lab[c] == 0); pos += (lab[c] == 1); }
    if (neg && pos != 1) { for (int c = 0; c < NCLS; c++) lab[c] = 0; }

    /* loss mask before -1 -> 0 squash */
    bool lm = false;
    for (int c = 0; c < NCLS; c++) lm |= (lab[c] != -1);

    float* G_cls = out + OFF_GCLS;
    float* G_reg = out + OFF_GREG;
    float* M_cls = out + OFF_MCLS;
    float* M_reg = out + OFF_MREG;

    M_cls[s] = lm ? 1.0f : 0.0f;

    for (int c = 0; c < NCLS; c++) {
        int L = (lab[c] == -1) ? 0 : lab[c];
        G_cls[c * NANCH + s] = (float)L;
        if (s < NYG * NXG) M_reg[c * (NYG * NXG) + s] = (float)L;  /* yaw==0 slice */

        float v0 = 0.f, v1 = 0.f, v2 = 0.f, v3 = 0.f, v4 = 0.f, v5 = 0.f, v6 = 0.f;
        if (L == 1) {
            const float* A = anchors + ((size_t)(c * NANCH + s)) * DOF;
            const float* G = boxes + (size_t)argmax[c * NANCH + s] * DOF;
            float nrm = sqrtf(A[3] * A[3] + A[4] * A[4]);
            v0 = (G[0] - A[0]) / nrm;
            v1 = (G[1] - A[1]) / nrm;
            v2 = (G[2] - A[2]) / A[5];
            v3 = logf(G[3] / A[3]);
            v4 = logf(G[4] / A[4]);
            v5 = logf(G[5] / A[5]);
            v6 = G[6] - A[6];
        }
        size_t rb = ((size_t)(c * NANCH + s)) * DOF;
        G_reg[rb + 0] = v0; G_reg[rb + 1] = v1; G_reg[rb + 2] = v2;
        G_reg[rb + 3] = v3; G_reg[rb + 4] = v4; G_reg[rb + 5] = v5;
        G_reg[rb + 6] = v6;
    }
}

extern "C" void kernel_launch(void* const* d_in, const int* in_sizes, int n_in,
                              void* d_out, int out_size, void* d_ws, size_t ws_size,
                              hipStream_t stream) {
    const float* boxes   = (const float*)d_in[0];
    const float* anchors = (const float*)d_in[1];
    const int*   cls     = (const int*)d_in[2];
    float* out = (float*)d_out;

    char* ws = (char*)d_ws;
    /* ws layout (bytes):
       [0, 19660800)          iou matrix f32 [3][32][51200]
       [19660800, 20275200)   maxval f32 [3][51200]
       [20275200, 20889600)   argmax i32 [3][51200]
       [20889600, 21504000)   labels i32 [3][51200]
       [21504000, 21504384)   highest f32 [3][32]                       */
    float* iou_mat = (float*)(ws);
    float* maxval  = (float*)(ws + 19660800);
    int*   argmax  = (int*)  (ws + 20275200);
    int*   labels  = (int*)  (ws + 20889600);
    float* highest = (float*)(ws + 21504000);

    hipMemsetAsync(highest, 0, NCLS * NB * sizeof(float), stream);

    iou_kernel<<<dim3((NCLS * NANCH) / 256), dim3(256), 0, stream>>>(
        boxes, anchors, cls, iou_mat, maxval, argmax, highest);
    label_kernel<<<dim3((NCLS * NANCH) / 256), dim3(256), 0, stream>>>(
        iou_mat, maxval, highest, cls, labels);
    out_kernel<<<dim3(NANCH / 256), dim3(256), 0, stream>>>(
        boxes, anchors, labels, argmax, out);
}